// Round 9
// baseline (240.764 us; speedup 1.0000x reference)
//
#include <hip/hip_runtime.h>

#define G 4096
#define P1_BLOCKS 1024   // 256 stripes x 4 col-quarters (32-row stripes)
#define P3_BLOCKS 2048   // 2 adj rows per block (32 KB)
#define NTHR 256

typedef float f4 __attribute__((ext_vector_type(4)));

// ws float offsets
#define OFF_PART 0          // part[256][4096] = 1048576 floats (4 MiB)
#define OFF_VMAG 1048576    // 4096 floats
#define OFF_ACC  1052672    // +0: acc_t (float)  +32: acc_n (int)  +64: ticket (uint)

#define AGENT __HIP_MEMORY_SCOPE_AGENT
#define RLX   __ATOMIC_RELAXED

// ---------------------------------------------------------------------------
// K1 (P1): |velocity| column sums over 256 stripes of 32 rows, NT loads
// (non-allocating: don't evict the harness's dirty poison -> no WB storm).
// Round-2-proven geometry/body + round-8-proven NT. Block 0 zeroes the K3
// accumulators (round-6-proven cross-dispatch init via kernel boundary).
// ---------------------------------------------------------------------------
__global__ __launch_bounds__(NTHR) void vmag_partial(const float* __restrict__ vel,
                                                     float* __restrict__ part,
                                                     float* __restrict__ acc) {
    if (blockIdx.x == 0 && threadIdx.x == 0) {
        acc[0] = 0.f;               // acc_t
        ((int*)acc)[32] = 0;        // acc_n
        ((unsigned*)acc)[64] = 0u;  // ticket
    }
    const int col0 = (blockIdx.x & 3) * 1024 + threadIdx.x * 4;
    const int stripe = blockIdx.x >> 2;   // 0..255
    const float* p = vel + (size_t)stripe * 32 * G + col0;
    float ax = 0.f, ay = 0.f, az = 0.f, aw = 0.f;
#pragma unroll 8
    for (int r = 0; r < 32; ++r) {
        f4 v = __builtin_nontemporal_load((const f4*)p);
        ax += fabsf(v.x); ay += fabsf(v.y); az += fabsf(v.z); aw += fabsf(v.w);
        p += G;
    }
    f4 o = {ax, ay, az, aw};
    *(f4*)(part + (size_t)stripe * G + col0) = o;  // cached: re-read by K2
}

// ---------------------------------------------------------------------------
// K2 (P2): 32 blocks; block b reduces cols [b*128,+128) over 256 stripes.
// Round-2-proven body (bit-identical summation order).
// ---------------------------------------------------------------------------
__global__ __launch_bounds__(NTHR) void vmag_reduce(const float* __restrict__ part,
                                                    float* __restrict__ vmag) {
    __shared__ f4 red[NTHR];
    const int t = threadIdx.x;
    const int c4 = t & 31;
    const int s0 = t >> 5;
    const int col0 = blockIdx.x * 128 + c4 * 4;
    f4 acc = {0.f, 0.f, 0.f, 0.f};
#pragma unroll
    for (int k = 0; k < 32; ++k)
        acc += *(const f4*)(part + (size_t)(s0 + 8 * k) * G + col0);
    red[t] = acc;  // red[s0*32 + c4]
    __syncthreads();
#pragma unroll
    for (int off = 128; off >= 32; off >>= 1) {
        if (t < off) red[t] += red[t + off];
        __syncthreads();
    }
    if (t < 32) {
        f4 a = red[t] * (1.0f / 8192.0f);
        *(f4*)(vmag + blockIdx.x * 128 + t * 4) = a;
    }
}

// ---------------------------------------------------------------------------
// K3 (P3+P4): pairwise pass (NT adj loads, round-8-proven body) + round-6-
// proven atomic-RMW finalize: every block atomicAdds its partial into
// acc_t/acc_n, drains vmcnt, takes a ticket; the last ticket re-reads the
// accumulators via fetch_add(...,0) (RMW reads execute at the coherence
// point) and writes out. No fences, no waiting, losers exit.
// ---------------------------------------------------------------------------
__global__ __launch_bounds__(NTHR) void pair_fin(const float* __restrict__ adj,
                                                 const float* __restrict__ vmag,
                                                 float* __restrict__ acc,
                                                 float* __restrict__ out) {
    const int tid = threadIdx.x;
    const int bid = blockIdx.x;

    f4 vjq[4];
#pragma unroll
    for (int q = 0; q < 4; ++q) vjq[q] = *(const f4*)(vmag + q * 1024 + tid * 4);
    const float vi0 = vmag[bid * 2];
    const float vi1 = vmag[bid * 2 + 1];

    const float* ablk = adj + (size_t)bid * 8192;
    float t = 0.f, nf = 0.f;
#pragma unroll
    for (int r = 0; r < 2; ++r) {
        const float vi = r ? vi1 : vi0;
        const float* arow = ablk + r * 4096;
#pragma unroll
        for (int q = 0; q < 4; ++q) {
            const f4 a = __builtin_nontemporal_load((const f4*)(arow + q * 1024 + tid * 4));
            const f4 vj = vjq[q];
            float a2;
            a2 = a.x * a.x; t = fmaf(fabsf(fmaf(a.x, -vi, vj.x)), a2, t); nf += a2;
            a2 = a.y * a.y; t = fmaf(fabsf(fmaf(a.y, -vi, vj.y)), a2, t); nf += a2;
            a2 = a.z * a.z; t = fmaf(fabsf(fmaf(a.z, -vi, vj.z)), a2, t); nf += a2;
            a2 = a.w * a.w; t = fmaf(fabsf(fmaf(a.w, -vi, vj.w)), a2, t); nf += a2;
        }
    }
#pragma unroll
    for (int off = 32; off > 0; off >>= 1) {
        t  += __shfl_down(t, off);
        nf += __shfl_down(nf, off);
    }
    __shared__ float st[4], snf[4];
    const int wave = tid >> 6;
    if ((tid & 63) == 0) { st[wave] = t; snf[wave] = nf; }
    __syncthreads();

    if (tid == 0) {
        const float T = st[0] + st[1] + st[2] + st[3];
        const int   N = (int)(snf[0] + snf[1] + snf[2] + snf[3]);  // exact: <= 8192
        float*    acc_t = acc;
        int*      acc_n = ((int*)acc) + 32;
        unsigned* cnt   = ((unsigned*)acc) + 64;

        (void)__hip_atomic_fetch_add(acc_t, T, RLX, AGENT);
        (void)__hip_atomic_fetch_add(acc_n, N, RLX, AGENT);
        asm volatile("s_waitcnt vmcnt(0)" ::: "memory");  // acc RMWs at LLC
        const unsigned tk = __hip_atomic_fetch_add(cnt, 1u, RLX, AGENT);
        if (tk == P3_BLOCKS - 1) {
            const float Tfin = __hip_atomic_fetch_add(acc_t, 0.0f, RLX, AGENT);
            const int   Nfin = __hip_atomic_fetch_add(acc_n, 0,    RLX, AGENT);
            out[0] = (Nfin > 0) ? (Tfin / fmaxf((float)Nfin, 1.f)) : 0.f;
        }
    }
}

extern "C" void kernel_launch(void* const* d_in, const int* in_sizes, int n_in,
                              void* d_out, int out_size, void* d_ws, size_t ws_size,
                              hipStream_t stream) {
    const float* vel = (const float*)d_in[0];
    // d_in[1] (perturbation_idx) unused by the reference.
    const float* adj = (const float*)d_in[2];
    float* wsf  = (float*)d_ws;
    float* part = wsf + OFF_PART;
    float* vmag = wsf + OFF_VMAG;
    float* acc  = wsf + OFF_ACC;
    float* out  = (float*)d_out;

    vmag_partial<<<P1_BLOCKS, NTHR, 0, stream>>>(vel, part, acc);
    vmag_reduce<<<32, NTHR, 0, stream>>>(part, vmag);
    pair_fin<<<P3_BLOCKS, NTHR, 0, stream>>>(adj, vmag, acc, out);
}